// Round 1
// baseline (955.324 us; speedup 1.0000x reference)
//
#include <hip/hip_runtime.h>
#include <hip/hip_cooperative_groups.h>

namespace cg = cooperative_groups;

// Capsule routing, factorized, all fp32.
// FUSED: one cooperative kernel (512 blocks x 256 threads, 2 blocks/CU), 11 grid.sync()
// replace 11 kernel boundaries. gemm1's Xs x-panel persists in LDS across all 4 iters.
// Fallback to the original 12-kernel path if cooperative launch fails.
// B=256, K_IN=8, C=1152, J=10, D=16, 4 iters.
// m = k*1152 + c (M=9216), n = j*16 + d (N=160).

#define C_IN  1152
#define J_U   10
#define M_DIM 9216
#define N_DIM 160
#define B_SZ  256

// ---- ws layout (float offsets); ws is 256 MiB so offsets are generous ----
#define OFF_XT   0                    // [9216][256]
#define OFF_WR   2400000              // [9216][160]
#define OFF_SP   3900000              // [128][256][160]
#define OFF_V    9200000              // [256][160]
#define OFF_B0   9250000              // [1152][10]
#define OFF_B1   9270000              // [1152][10]
#define OFF_AG   9290000              // [32][1152][10]

// ======================= fused cooperative kernel =======================
// LDS budget: Xs 18432 B (persistent) + S 51840 B (overlay) = 70272 B -> 2 blocks/CU.
// S overlay: prep T[64][65] (16.6KB) | gemm1 Ws 46KB + braw/csm 5.8KB | squash 1.9KB
//            | gemm2 VG 41.9KB + agg 2.6KB
__global__ __launch_bounds__(256, 2) void k_fused(const float* __restrict__ x,
                                                  const float* __restrict__ W,
                                                  float* __restrict__ ws,
                                                  float* __restrict__ out) {
    cg::grid_group grid = cg::this_grid();
    const int bid = blockIdx.x, t = threadIdx.x;
    float* Xt   = ws + OFF_XT;
    float* Wr   = ws + OFF_WR;
    float* sp   = ws + OFF_SP;
    float* vv   = ws + OFF_V;
    float* bij0 = ws + OFF_B0;
    float* bij1 = ws + OFF_B1;
    float* aggp = ws + OFF_AG;

    __shared__ alignas(16) float Xs[72 * 64];   // persistent gemm1 x-panel
    __shared__ alignas(16) float S[12960];      // overlay region

    // ---------------- phase 0: prep (Xt transpose + Wr build) ----------------
    for (int w = bid; w < 2016; w += 512) {
        if (w < 576) {                       // 144 m-tiles x 4 b-tiles, 64x64 transpose
            float (*T)[65] = reinterpret_cast<float(*)[65]>(S);
            const int m0p = (w % 144) * 64, b0p = (w / 144) * 64;
            __syncthreads();                 // protect T reuse across strided units
            {
                const int b_l = t >> 2, q = t & 3;
                const float* xp = x + (size_t)(b0p + b_l) * M_DIM + m0p + q * 16;
#pragma unroll
                for (int u = 0; u < 4; ++u) {
                    const float4 v4 = *reinterpret_cast<const float4*>(xp + 4 * u);
                    T[q * 16 + 4 * u + 0][b_l] = v4.x;
                    T[q * 16 + 4 * u + 1][b_l] = v4.y;
                    T[q * 16 + 4 * u + 2][b_l] = v4.z;
                    T[q * 16 + 4 * u + 3][b_l] = v4.w;
                }
            }
            __syncthreads();
            {
                const int m_l = t >> 2, q = t & 3;
                float4* op = reinterpret_cast<float4*>(Xt + (size_t)(m0p + m_l) * B_SZ + b0p + q * 16);
#pragma unroll
                for (int u = 0; u < 4; ++u)
                    op[u] = make_float4(T[m_l][q * 16 + 4 * u], T[m_l][q * 16 + 4 * u + 1],
                                        T[m_l][q * 16 + 4 * u + 2], T[m_l][q * 16 + 4 * u + 3]);
            }
        } else {                             // Wr[(k*C+c)][n] = W[c][n][k]
            const int i = (w - 576) * 256 + t;      // [0, 368640)
            const int n = i % N_DIM;
            const int c = (i / N_DIM) % C_IN;
            const int kh = i / (N_DIM * C_IN);      // 0..1
            const float4 w4 = *reinterpret_cast<const float4*>(W + (size_t)c * 1280 + n * 8 + kh * 4);
            const float warr[4] = {w4.x, w4.y, w4.z, w4.w};
#pragma unroll
            for (int j = 0; j < 4; ++j)
                Wr[(size_t)((kh * 4 + j) * C_IN + c) * N_DIM + n] = warr[j];
        }
    }
    grid.sync();

    // -------- per-block identity for gemm1 (fixed across iterations) --------
    const int ch = bid >> 2, bq4 = bid & 3;
    const int m0 = ch * 72;
    const int c0 = (ch & 15) * 72;        // chunk sits inside one k-slice (1152/72=16)
    float* Ws   = S;                      // 11520 floats (float4-aligned)
    float* braw = S + 11520;              // 720
    float* csm  = S + 12240;              // 720
    const float4* Wr4 = reinterpret_cast<const float4*>(Wr);

    for (int it = 0; it < 4; ++it) {
        const float* bo = (it & 1) ? bij1 : bij0;
        float*       bn = (it & 1) ? bij0 : bij1;

        // ================= gemm1 =================
        if (it == 0) {
            // b_ij == 0: softmax(0) = 1/J exactly; skip the 32-slice agg read.
            for (int idx = t; idx < 720; idx += 256) {
                csm[idx] = 0.1f;
                bn[c0 * J_U + idx] = 0.f;
            }
            // stage persistent x panel ONCE (72 rows x 16 float4, 64 b each)
            for (int i = t; i < 1152; i += 256) {
                const int row = i >> 4, col = i & 15;
                const float4 xv = *reinterpret_cast<const float4*>(
                    Xt + (size_t)(m0 + row) * B_SZ + bq4 * 64 + col * 4);
                *reinterpret_cast<float4*>(&Xs[row * 64 + col * 4]) = xv;
            }
        } else {
            for (int idx = t; idx < 720; idx += 256) {
                float b_v = bo[c0 * J_U + idx];
#pragma unroll
                for (int s = 0; s < 32; ++s) b_v += aggp[s * 11520 + c0 * J_U + idx];
                braw[idx] = b_v;
                bn[c0 * J_U + idx] = b_v;
            }
            __syncthreads();
            for (int idx = t; idx < 720; idx += 256) {    // softmax over j
                const int r0 = (idx / J_U) * J_U;
                float mx = -1e30f;
#pragma unroll
                for (int j = 0; j < J_U; ++j) mx = fmaxf(mx, braw[r0 + j]);
                float sum = 0.f;
#pragma unroll
                for (int j = 0; j < J_U; ++j) sum += __expf(braw[r0 + j] - mx);
                csm[idx] = __expf(braw[idx] - mx) / sum;
            }
        }
        __syncthreads();
        // ---- stage scaled W panel ----
        {
            float4* Ws4 = reinterpret_cast<float4*>(Ws);
            for (int i = t; i < 2880; i += 256) {          // 72 rows x 40 float4
                const int row = i / 40, q = i - row * 40;
                const float sc = csm[row * J_U + (q >> 2)];
                const float4 w4 = Wr4[(size_t)(m0 + row) * 40 + q];
                Ws4[i] = make_float4(w4.x * sc, w4.y * sc, w4.z * sc, w4.w * sc);
            }
        }
        __syncthreads();
        // ---- main loop: pure LDS (x b128 conflict-free, w b64 broadcast) ----
        {
            const int bq = t & 15, ng = t >> 4;
            float acc[4][10] = {};
#pragma unroll 4
            for (int m = 0; m < 72; ++m) {
                const float4 cur = *reinterpret_cast<const float4*>(&Xs[m * 64 + bq * 4]);
                const float2* wr2 = reinterpret_cast<const float2*>(Ws + m * N_DIM + ng * J_U);
                const float xv[4] = {cur.x, cur.y, cur.z, cur.w};
#pragma unroll
                for (int jj = 0; jj < 5; ++jj) {
                    const float2 w2 = wr2[jj];
#pragma unroll
                    for (int i = 0; i < 4; ++i) {
                        acc[i][2 * jj]     += xv[i] * w2.x;
                        acc[i][2 * jj + 1] += xv[i] * w2.y;
                    }
                }
            }
            float* spp = sp + (size_t)ch * 40960 + (size_t)(bq4 * 64 + bq * 4) * N_DIM + ng * J_U;
#pragma unroll
            for (int i = 0; i < 4; ++i) {
                float2* p2 = reinterpret_cast<float2*>(spp + (size_t)i * N_DIM);
#pragma unroll
                for (int jj = 0; jj < 5; ++jj) p2[jj] = make_float2(acc[i][2 * jj], acc[i][2 * jj + 1]);
            }
        }
        grid.sync();                 // s_part complete

        // ================= squash (blocks 0..255, one b each) =================
        if (bid < B_SZ) {
            float* red = S;          // 320
            float* sq  = S + 320;    // 160
            float* dst = (it < 3) ? vv : out;
            // 320 work items over 256 threads: item i -> (n = i%160, h = i/160)
            for (int i2 = t; i2 < 320; i2 += 256) {
                const int n = i2 % 160, h = i2 / 160;
                float s_ = 0.f;
                const float* p = sp + (size_t)h * 64 * 40960 + (size_t)bid * N_DIM + n;
#pragma unroll 8
                for (int sl = 0; sl < 64; ++sl) s_ += p[(size_t)sl * 40960];
                red[i2] = s_;
            }
            __syncthreads();
            if (t < 160) {
                const float s_ = red[t] + red[t + 160] + 1e-5f;   // +1e-5 BEFORE magnitudes
                sq[t] = s_ * s_;
                red[t] = s_;
            }
            __syncthreads();
            if (t < 160) {
                const int j0 = t & ~15;
                float mag = 0.f;
#pragma unroll
                for (int d = 0; d < 16; ++d) mag += sq[j0 + d];
                dst[(size_t)bid * N_DIM + t] = red[t] * (sqrtf(mag) / (1.f + mag));
            }
        }
        if (it == 3) break;          // uniform across grid; last agreement unused
        grid.sync();                 // v complete

        // ================= gemm2 (576 tiles strided over 512 blocks) =================
        for (int tile = bid; tile < 576; tile += 512) {
            const int mt = tile >> 2, bq2 = tile & 3;
            const int m02 = mt * 64, b0 = bq2 * 64;
            const int tm = t & 15, ng = t >> 4;
            float* VG  = S;          // 64*164 floats
            float* agg = S + 10496;  // 640 floats
            __syncthreads();         // protect S reuse (squash / previous tile)
            // stage v quarter (packed [64][160])
            float4* Vs4 = reinterpret_cast<float4*>(VG);
            const float4* v4 = reinterpret_cast<const float4*>(vv);
            for (int i = t; i < 2560; i += 256) Vs4[i] = v4[(size_t)bq2 * 2560 + i];
            for (int i = t; i < 640; i += 256) agg[i] = 0.f;
            __syncthreads();
            // main loop over 64 b: x coalesced, v broadcast from LDS
            float acc[4][10] = {};
            const float* xb = x + (size_t)b0 * M_DIM + m02 + tm * 4;
            const float2* Vs2 = reinterpret_cast<const float2*>(VG);
            float4 pf[4];
#pragma unroll
            for (int i = 0; i < 4; ++i) pf[i] = *reinterpret_cast<const float4*>(xb + (size_t)i * M_DIM);
#pragma unroll 4
            for (int b = 0; b < 64; ++b) {
                const int bf = (b + 4 < 64) ? b + 4 : 63;            // clamped prefetch
                const float4 nxt = *reinterpret_cast<const float4*>(xb + (size_t)bf * M_DIM);
                const float4 cur = pf[0];
                pf[0] = pf[1]; pf[1] = pf[2]; pf[2] = pf[3]; pf[3] = nxt;
                const float2* vr = Vs2 + b * 80 + ng * 5;
                const float xv[4] = {cur.x, cur.y, cur.z, cur.w};
#pragma unroll
                for (int jj = 0; jj < 5; ++jj) {
                    const float2 w2 = vr[jj];
#pragma unroll
                    for (int i = 0; i < 4; ++i) {
                        acc[i][2 * jj]     += xv[i] * w2.x;
                        acc[i][2 * jj + 1] += xv[i] * w2.y;
                    }
                }
            }
            __syncthreads();         // all waves done reading v-panel; reuse VG
            // scatter acc -> G-tile (row stride 164 floats, 16B-aligned rows)
#pragma unroll
            for (int i = 0; i < 4; ++i)
#pragma unroll
                for (int q = 0; q < 10; ++q)
                    VG[(tm * 4 + i) * 164 + ng * 10 + q] = acc[i][q];
            __syncthreads();
            // coalesced fold: 64 rows x 40 float4 of Wr ⊙ G, one j per float4
            for (int idx = t; idx < 2560; idx += 256) {
                const int row = idx / 40, q = idx - row * 40;
                const float4 w4 = Wr4[(size_t)(m02 + row) * 40 + q];
                const float4 g = *reinterpret_cast<const float4*>(&VG[row * 164 + q * 4]);
                atomicAdd(&agg[row * J_U + (q >> 2)],
                          w4.x * g.x + w4.y * g.y + w4.z * g.z + w4.w * g.w);
            }
            __syncthreads();
            const int k = m02 / C_IN, c02 = m02 - k * C_IN;   // 64-tile never crosses k-slice
            for (int i = t; i < 640; i += 256)
                aggp[(size_t)(bq2 * 8 + k) * 11520 + c02 * J_U + i] = agg[i];
        }
        grid.sync();                 // agg_part complete
    }
}

// ======================= fallback: original 12-kernel path =======================
__global__ __launch_bounds__(256) void k_prep(const float* __restrict__ x,
                                              const float* __restrict__ W,
                                              float* __restrict__ ws) {
    const int bid = blockIdx.x, t = threadIdx.x;
    if (bid < 576) {
        __shared__ float T[64][65];
        const int m0 = (bid % 144) * 64, b0 = (bid / 144) * 64;
        {
            const int b_l = t >> 2, q = t & 3;
            const float* xp = x + (size_t)(b0 + b_l) * M_DIM + m0 + q * 16;
#pragma unroll
            for (int u = 0; u < 4; ++u) {
                const float4 v = *reinterpret_cast<const float4*>(xp + 4 * u);
                T[q * 16 + 4 * u + 0][b_l] = v.x;
                T[q * 16 + 4 * u + 1][b_l] = v.y;
                T[q * 16 + 4 * u + 2][b_l] = v.z;
                T[q * 16 + 4 * u + 3][b_l] = v.w;
            }
        }
        __syncthreads();
        {
            const int m_l = t >> 2, q = t & 3;
            float* Xt = ws + OFF_XT;
            float4* op = reinterpret_cast<float4*>(Xt + (size_t)(m0 + m_l) * B_SZ + b0 + q * 16);
#pragma unroll
            for (int u = 0; u < 4; ++u)
                op[u] = make_float4(T[m_l][q * 16 + 4 * u], T[m_l][q * 16 + 4 * u + 1],
                                    T[m_l][q * 16 + 4 * u + 2], T[m_l][q * 16 + 4 * u + 3]);
        }
    } else {
        const int i = (bid - 576) * 256 + t;
        const int n = i % N_DIM;
        const int c = (i / N_DIM) % C_IN;
        const int kh = i / (N_DIM * C_IN);
        const float4 w = *reinterpret_cast<const float4*>(W + (size_t)c * 1280 + n * 8 + kh * 4);
        float* Wr = ws + OFF_WR;
        const float wv[4] = {w.x, w.y, w.z, w.w};
#pragma unroll
        for (int j = 0; j < 4; ++j)
            Wr[(size_t)((kh * 4 + j) * C_IN + c) * N_DIM + n] = wv[j];
    }
}

__global__ __launch_bounds__(256, 2) void k_gemm1(const float* __restrict__ Xt,
                                                  const float4* __restrict__ Wr4,
                                                  const float* __restrict__ bij_old,
                                                  float* __restrict__ bij_new,
                                                  const float* __restrict__ agg_part,
                                                  float* __restrict__ s_part,
                                                  int first) {
    __shared__ float braw[720];
    __shared__ float csm[720];
    __shared__ float Ws[72 * 160];
    __shared__ alignas(16) float Xs[72 * 64];
    const int ch = blockIdx.x >> 2, bq4 = blockIdx.x & 3;
    const int m0 = ch * 72;
    const int c0 = (ch & 15) * 72;
    const int t = threadIdx.x;

    if (first) {
        for (int idx = t; idx < 720; idx += 256) {
            csm[idx] = 0.1f;
            bij_new[c0 * J_U + idx] = 0.f;
        }
    } else {
        for (int idx = t; idx < 720; idx += 256) {
            float v = bij_old[c0 * J_U + idx];
#pragma unroll
            for (int s = 0; s < 32; ++s) v += agg_part[s * 11520 + c0 * J_U + idx];
            braw[idx] = v;
            bij_new[c0 * J_U + idx] = v;
        }
        __syncthreads();
        for (int idx = t; idx < 720; idx += 256) {
            const int r0 = (idx / J_U) * J_U;
            float mx = -1e30f;
#pragma unroll
            for (int j = 0; j < J_U; ++j) mx = fmaxf(mx, braw[r0 + j]);
            float sum = 0.f;
#pragma unroll
            for (int j = 0; j < J_U; ++j) sum += __expf(braw[r0 + j] - mx);
            csm[idx] = __expf(braw[idx] - mx) / sum;
        }
    }
    __syncthreads();
    float4* Ws4 = reinterpret_cast<float4*>(Ws);
    for (int i = t; i < 2880; i += 256) {
        const int row = i / 40, q = i - row * 40;
        const float sc = csm[row * J_U + (q >> 2)];
        const float4 w = Wr4[(size_t)(m0 + row) * 40 + q];
        Ws4[i] = make_float4(w.x * sc, w.y * sc, w.z * sc, w.w * sc);
    }
    for (int i = t; i < 1152; i += 256) {
        const int row = i >> 4, col = i & 15;
        const float4 xv = *reinterpret_cast<const float4*>(
            Xt + (size_t)(m0 + row) * B_SZ + bq4 * 64 + col * 4);
        *reinterpret_cast<float4*>(&Xs[row * 64 + col * 4]) = xv;
    }
    __syncthreads();
    const int bq = t & 15, ng = t >> 4;
    float acc[4][10] = {};
#pragma unroll 4
    for (int m = 0; m < 72; ++m) {
        const float4 cur = *reinterpret_cast<const float4*>(&Xs[m * 64 + bq * 4]);
        const float2* wr = reinterpret_cast<const float2*>(Ws + m * N_DIM + ng * J_U);
        const float xv[4] = {cur.x, cur.y, cur.z, cur.w};
#pragma unroll
        for (int jj = 0; jj < 5; ++jj) {
            const float2 wv = wr[jj];
#pragma unroll
            for (int i = 0; i < 4; ++i) {
                acc[i][2 * jj]     += xv[i] * wv.x;
                acc[i][2 * jj + 1] += xv[i] * wv.y;
            }
        }
    }
    float* sp = s_part + (size_t)ch * 40960 + (size_t)(bq4 * 64 + bq * 4) * N_DIM + ng * J_U;
#pragma unroll
    for (int i = 0; i < 4; ++i) {
        float2* p = reinterpret_cast<float2*>(sp + (size_t)i * N_DIM);
#pragma unroll
        for (int jj = 0; jj < 5; ++jj) p[jj] = make_float2(acc[i][2 * jj], acc[i][2 * jj + 1]);
    }
}

__global__ __launch_bounds__(320) void k_squash(const float* __restrict__ s_part,
                                                float* __restrict__ dst) {
    __shared__ float red[320];
    __shared__ float sq[160];
    const int b = blockIdx.x, t = threadIdx.x;
    const int n = t % 160, h = t / 160;
    float s = 0.f;
    const float* p = s_part + (size_t)h * 64 * 40960 + (size_t)b * N_DIM + n;
#pragma unroll 8
    for (int sl = 0; sl < 64; ++sl) s += p[(size_t)sl * 40960];
    red[t] = s;
    __syncthreads();
    if (t < 160) {
        s = red[t] + red[t + 160] + 1e-5f;
        sq[t] = s * s;
        red[t] = s;
    }
    __syncthreads();
    if (t < 160) {
        const int j0 = t & ~15;
        float mag = 0.f;
#pragma unroll
        for (int d = 0; d < 16; ++d) mag += sq[j0 + d];
        dst[(size_t)b * N_DIM + t] = red[t] * (sqrtf(mag) / (1.f + mag));
    }
}

__global__ __launch_bounds__(256) void k_gemm2(const float* __restrict__ x,
                                               const float* __restrict__ v,
                                               const float* __restrict__ Wr,
                                               float* __restrict__ agg_part) {
    __shared__ alignas(16) float VG[64 * 164];
    __shared__ float agg[640];
    const int mt = blockIdx.x >> 2, bq = blockIdx.x & 3;
    const int m0 = mt * 64, b0 = bq * 64;
    const int t = threadIdx.x;
    const int tm = t & 15, ng = t >> 4;

    float4* Vs4 = reinterpret_cast<float4*>(VG);
    const float4* v4 = reinterpret_cast<const float4*>(v);
    for (int i = t; i < 2560; i += 256) Vs4[i] = v4[(size_t)bq * 2560 + i];
    for (int i = t; i < 640; i += 256) agg[i] = 0.f;
    __syncthreads();

    float acc[4][10] = {};
    const float* xb = x + (size_t)b0 * M_DIM + m0 + tm * 4;
    const float2* Vs2 = reinterpret_cast<const float2*>(VG);
    float4 pf[4];
#pragma unroll
    for (int i = 0; i < 4; ++i) pf[i] = *reinterpret_cast<const float4*>(xb + (size_t)i * M_DIM);
#pragma unroll 4
    for (int b = 0; b < 64; ++b) {
        const int bf = (b + 4 < 64) ? b + 4 : 63;
        const float4 nxt = *reinterpret_cast<const float4*>(xb + (size_t)bf * M_DIM);
        const float4 cur = pf[0];
        pf[0] = pf[1]; pf[1] = pf[2]; pf[2] = pf[3]; pf[3] = nxt;
        const float2* vv = Vs2 + b * 80 + ng * 5;
        const float xv[4] = {cur.x, cur.y, cur.z, cur.w};
#pragma unroll
        for (int jj = 0; jj < 5; ++jj) {
            const float2 w = vv[jj];
#pragma unroll
            for (int i = 0; i < 4; ++i) {
                acc[i][2 * jj]     += xv[i] * w.x;
                acc[i][2 * jj + 1] += xv[i] * w.y;
            }
        }
    }
    __syncthreads();
#pragma unroll
    for (int i = 0; i < 4; ++i)
#pragma unroll
        for (int q = 0; q < 10; ++q)
            VG[(tm * 4 + i) * 164 + ng * 10 + q] = acc[i][q];
    __syncthreads();
    const float4* Wr4 = reinterpret_cast<const float4*>(Wr);
    for (int idx = t; idx < 2560; idx += 256) {
        const int row = idx / 40, q = idx - row * 40;
        const float4 w = Wr4[(size_t)(m0 + row) * 40 + q];
        const float4 g = *reinterpret_cast<const float4*>(&VG[row * 164 + q * 4]);
        atomicAdd(&agg[row * J_U + (q >> 2)], w.x * g.x + w.y * g.y + w.z * g.z + w.w * g.w);
    }
    __syncthreads();
    const int k = m0 / C_IN, c0 = m0 - k * C_IN;
    for (int i = t; i < 640; i += 256)
        agg_part[(size_t)(bq * 8 + k) * 11520 + c0 * J_U + i] = agg[i];
}

extern "C" void kernel_launch(void* const* d_in, const int* in_sizes, int n_in,
                              void* d_out, int out_size, void* d_ws, size_t ws_size,
                              hipStream_t stream) {
    const float* x = (const float*)d_in[0];   // (256, 8, 1152) fp32
    const float* W = (const float*)d_in[1];   // (1, 1152, 10, 16, 8) fp32
    float* out = (float*)d_out;               // (256, 10, 16, 1) fp32
    float* ws  = (float*)d_ws;

    void* args[] = {(void*)&x, (void*)&W, (void*)&ws, (void*)&out};
    hipError_t err = hipLaunchCooperativeKernel((const void*)k_fused, dim3(512), dim3(256),
                                                args, 0, stream);
    if (err == hipSuccess) return;

    // ---- fallback: original 12-kernel sequence ----
    float* Xt   = ws + OFF_XT;
    float* Wr   = ws + OFF_WR;
    float* sp   = ws + OFF_SP;
    float* v    = ws + OFF_V;
    float* bij0 = ws + OFF_B0;
    float* bij1 = ws + OFF_B1;
    float* agg  = ws + OFF_AG;
    const float4* Wr4 = (const float4*)Wr;

    k_prep<<<2016, 256, 0, stream>>>(x, W, ws);
    for (int it = 0; it < 4; ++it) {
        const float* bo = (it & 1) ? bij1 : bij0;
        float*       bn = (it & 1) ? bij0 : bij1;
        k_gemm1<<<512, 256, 0, stream>>>(Xt, Wr4, bo, bn, agg, sp, it == 0 ? 1 : 0);
        k_squash<<<256, 320, 0, stream>>>(sp, (it < 3) ? v : out);
        if (it < 3)
            k_gemm2<<<576, 256, 0, stream>>>(x, v, Wr, agg);
    }
}